// Round 3
// baseline (344.189 us; speedup 1.0000x reference)
//
#include <hip/hip_runtime.h>
#include <hip/hip_bf16.h>

typedef unsigned short u16;
typedef short short8 __attribute__((ext_vector_type(8)));
typedef float f32x4 __attribute__((ext_vector_type(4)));

// ---------------- helpers ----------------
static __device__ __forceinline__ u16 f2bf(float f) {
  unsigned u = __builtin_bit_cast(unsigned, f);
  unsigned r = (u + 0x7fffu + ((u >> 16) & 1u)) >> 16;  // RTNE
  return (u16)r;
}
static __device__ __forceinline__ float bf2f(u16 h) {
  unsigned u = ((unsigned)h) << 16;
  return __builtin_bit_cast(float, u);
}

// fast hw trig: v_sin_f32/v_cos_f32 take REVOLUTIONS, need explicit fract
static __device__ __forceinline__ float fsin(float x) {
  float r = x * 0.15915494309189535f;
  r = r - floorf(r);
  return __builtin_amdgcn_sinf(r);
}
static __device__ __forceinline__ float fcos(float x) {
  float r = x * 0.15915494309189535f;
  r = r - floorf(r);
  return __builtin_amdgcn_cosf(r);
}

// ---------------- weight prep: w = g * v / ||v_row||, store [N][Kpad] bf16 ----------------
__global__ void prep_w_bf16(const float* __restrict__ v, const float* __restrict__ g,
                            u16* __restrict__ out, int fan_in, int kpad) {
  const int row = blockIdx.x;
  const int lane = threadIdx.x;
  double s = 0.0;
  for (int k = lane; k < fan_in; k += 64) {
    double x = (double)v[(size_t)row * fan_in + k];
    s += x * x;
  }
#pragma unroll
  for (int off = 32; off; off >>= 1) s += __shfl_xor(s, off);
  double scale = (double)g[row] / sqrt(s);
  for (int k = lane; k < kpad; k += 64) {
    float wv = (k < fan_in) ? (float)((double)v[(size_t)row * fan_in + k] * scale) : 0.0f;
    out[(size_t)row * kpad + k] = f2bf(wv);
  }
}

__global__ void prep_w_f32(const float* __restrict__ v, const float* __restrict__ g,
                           float* __restrict__ out, int fan_in) {
  const int row = blockIdx.x;
  const int lane = threadIdx.x;
  double s = 0.0;
  for (int k = lane; k < fan_in; k += 64) {
    double x = (double)v[(size_t)row * fan_in + k];
    s += x * x;
  }
#pragma unroll
  for (int off = 32; off; off >>= 1) s += __shfl_xor(s, off);
  double scale = (double)g[row] / sqrt(s);
  for (int k = lane; k < fan_in; k += 64) {
    out[(size_t)row * fan_in + k] = (float)((double)v[(size_t)row * fan_in + k] * scale);
  }
}

// ---------------- stats: one LANE per point ----------------
// Pbuf layout per point (12 f32): density, spx,spy,spz, vax,vay,vaz, sdx,sdy,sdz, 0,0
__global__ __launch_bounds__(256) void stats_kernel(
    const float* __restrict__ pts, const float* __restrict__ phys,
    const float* __restrict__ cam, float* __restrict__ Pbuf) {
  const int i = blockIdx.x * 256 + threadIdx.x;

  const double qx = (double)pts[i * 3 + 0];
  const double qy = (double)pts[i * 3 + 1];
  const double qz = (double)pts[i * 3 + 2];

  int cnt = 0, nnn = 0;
  double w_sum = 0, wpx = 0, wpy = 0, wpz = 0;
  double Sx = 0, Sy = 0, Sz = 0, Qx = 0, Qy = 0, Qz = 0;

  // ordered first-20-valid scan; j is wave-uniform -> phys loads are scalar
  for (int j = 0; j < 4096; ++j) {
    const double px = (double)phys[j * 3 + 0];
    const double py = (double)phys[j * 3 + 1];
    const double pz = (double)phys[j * 3 + 2];
    const double dx = px - qx, dy = py - qy, dz = pz - qz;
    const double d2 = dx * dx + dy * dy + dz * dz;   // fp64: selection must match np ref
    if (d2 < 81.0 && cnt < 20) {
      const float d2f = (float)d2;
      float wf = 1.0f - d2f * sqrtf(d2f) * (1.0f / 729.0f);
      if (wf < 0.0f) wf = 0.0f;
      const double w = (double)wf;
      w_sum += w; wpx += w * px; wpy += w * py; wpz += w * pz;
      if (d2 != 0.0) {
        nnn += 1;
        Sx += dx; Sy += dy; Sz += dz;
        Qx += dx * dx; Qy += dy * dy; Qz += dz * dz;
      }
      cnt += 1;
    }
    if (!__any(cnt < 20)) break;
  }

  // padding slots: neighbors = 0 -> dd = ||q||
  {
    const float q2f = (float)(qx * qx + qy * qy + qz * qz);
    float wpad = 1.0f - q2f * sqrtf(q2f) * (1.0f / 729.0f);
    if (wpad < 0.0f) wpad = 0.0f;
    w_sum += (double)(20 - cnt) * (double)wpad;
  }

  const double inv_denom = 1.0 / (w_sum + 1e-12);
  const double sposx = wpx * inv_denom, sposy = wpy * inv_denom, sposz = wpz * inv_denom;

  const double inv_nd = 1.0 / ((double)nnn + 1e-12);
  const double vmx = Sx * inv_nd, vmy = Sy * inv_nd, vmz = Sz * inv_nd;
  const float vax = (float)((Qx - 2.0 * vmx * Sx + (double)nnn * vmx * vmx) * inv_nd);
  const float vay = (float)((Qy - 2.0 * vmy * Sy + (double)nnn * vmy * vmy) * inv_nd);
  const float vaz = (float)((Qz - 2.0 * vmz * Sz + (double)nnn * vmz * vmz) * inv_nd);

  const double ddx = sposx - (double)cam[0];
  const double ddy = sposy - (double)cam[1];
  const double ddz = sposz - (double)cam[2];
  const double inv_dnm = 1.0 / sqrt(ddx * ddx + ddy * ddy + ddz * ddz);

  f32x4* out = (f32x4*)(Pbuf + (size_t)i * 12);
  f32x4 o0, o1, o2;
  o0[0] = (float)w_sum; o0[1] = (float)sposx; o0[2] = (float)sposy; o0[3] = (float)sposz;
  o1[0] = vax; o1[1] = vay; o1[2] = vaz; o1[3] = (float)(ddx * inv_dnm);
  o2[0] = (float)(ddy * inv_dnm); o2[1] = (float)(ddz * inv_dnm); o2[2] = 0.0f; o2[3] = 0.0f;
  out[0] = o0; out[1] = o1; out[2] = o2;
}

// ---------------- embeddings ----------------
static __device__ __forceinline__ float embed3(float a, float b, float c, int e) {
  // layout: [a,b,c, sin(2^0 a),sin(2^0 b),sin(2^0 c),cos(2^0 a),..., f=0..F-1]
  if (e < 3) return e == 0 ? a : (e == 1 ? b : c);
  int u = e - 3;
  int f = u / 6;
  int r = u - f * 6;
  int ci = r % 3;
  float x = ci == 0 ? a : (ci == 1 ? b : c);
  float xf = x * (float)(1 << f);   // exact (power of 2)
  return (r < 3) ? fsin(xf) : fcos(xf);
}
static __device__ __forceinline__ float embed1(float a, int e) {
  if (e == 0) return a;
  int u = e - 1;
  int f = u >> 1;
  float xf = a * (float)(1 << f);
  return (u & 1) ? fcos(xf) : fsin(xf);
}

// ---------------- embed + write X: one wave per point ----------------
// X row layout (576 cols, zero pad beyond 517):
// [0:3) points  [3:6) view_dirs  [6:9) normals  [9:265) feature_vectors
// [265:328) emb(points,10) [328:337) emb(density,4) [337:400) emb(spos,10)
// [400:463) emb(var,10) [463:490) emb(ray_dir,4) [490:517) emb(sdir,4)
__global__ __launch_bounds__(256) void emb_kernel(
    const float* __restrict__ pts, const float* __restrict__ nrm,
    const float* __restrict__ vdir, const float* __restrict__ fv,
    const float* __restrict__ rdir, const float* __restrict__ Pbuf,
    u16* __restrict__ X) {
  const int m = (int)((blockIdx.x * blockDim.x + threadIdx.x) >> 6);
  const int lane = (int)(threadIdx.x & 63);

  const f32x4* pb = (const f32x4*)(Pbuf + (size_t)m * 12);
  const f32x4 s0 = pb[0];
  const f32x4 s1 = pb[1];
  const f32x4 s2 = pb[2];
  const float density = s0[0];
  const float spx = s0[1], spy = s0[2], spz = s0[3];
  const float vax = s1[0], vay = s1[1], vaz = s1[2];
  const float sdx = s1[3], sdy = s2[0], sdz = s2[1];

  const float fqx = pts[m * 3 + 0], fqy = pts[m * 3 + 1], fqz = pts[m * 3 + 2];
  const int ray = m >> 7;  // reps = 32768/256 = 128
  const float rdx = rdir[ray * 3 + 0], rdy = rdir[ray * 3 + 1], rdz = rdir[ray * 3 + 2];

  u16* __restrict__ xrow = X + (size_t)m * 576;
  for (int k = lane; k < 576; k += 64) {
    float val;
    if (k < 9) {
      if (k < 3) val = (k == 0) ? fqx : (k == 1 ? fqy : fqz);
      else if (k < 6) val = vdir[m * 3 + (k - 3)];
      else val = nrm[m * 3 + (k - 6)];
    } else if (k < 265) {
      val = fv[(size_t)m * 256 + (k - 9)];
    } else if (k < 328) {
      val = embed3(fqx, fqy, fqz, k - 265);
    } else if (k < 337) {
      val = embed1(density, k - 328);
    } else if (k < 400) {
      val = embed3(spx, spy, spz, k - 337);
    } else if (k < 463) {
      val = embed3(vax, vay, vaz, k - 400);
    } else if (k < 490) {
      val = embed3(rdx, rdy, rdz, k - 463);
    } else if (k < 517) {
      val = embed3(sdx, sdy, sdz, k - 490);
    } else {
      val = 0.0f;
    }
    xrow[k] = f2bf(val);
  }
}

// ---------------- bf16 MFMA GEMM: C[M,512] = relu(A[M,K] * B[N,K]^T + bias) ----------------
// A row-major stride K; B (weights) row-major [N][K]; C bf16 [M][512].
// Block: 256 threads = 4 waves (2x2), tile 128x128, BK=64.
template <int KTILES>
__global__ __launch_bounds__(256) void gemm_relu(const u16* __restrict__ A,
                                                 const u16* __restrict__ B,
                                                 const float* __restrict__ bias,
                                                 u16* __restrict__ C) {
  constexpr int K = KTILES * 64;
  __shared__ __align__(16) u16 As[128][72];  // +8 pad: 2-way (free) bank pattern
  __shared__ __align__(16) u16 Bs[128][72];

  const int t = threadIdx.x;
  const int lane = t & 63;
  const int wid = t >> 6;
  const int wm = wid >> 1, wn = wid & 1;
  const int n0 = blockIdx.x * 128;
  const int m0 = blockIdx.y * 128;

  f32x4 acc[4][4] = {};

  for (int kt = 0; kt < KTILES; ++kt) {
    const int k0 = kt * 64;
    __syncthreads();
#pragma unroll
    for (int i = 0; i < 4; ++i) {
      int slot = i * 256 + t;       // 0..1023
      int rr = slot >> 3;           // 0..127
      int cc = slot & 7;            // 0..7 (16B chunks)
      short8 av = *(const short8*)(A + (size_t)(m0 + rr) * K + k0 + cc * 8);
      short8 bv = *(const short8*)(B + (size_t)(n0 + rr) * K + k0 + cc * 8);
      *(short8*)&As[rr][cc * 8] = av;
      *(short8*)&Bs[rr][cc * 8] = bv;
    }
    __syncthreads();
#pragma unroll
    for (int ks = 0; ks < 2; ++ks) {
      short8 af[4], bfv[4];
#pragma unroll
      for (int f = 0; f < 4; ++f) {
        af[f] = *(const short8*)&As[wm * 64 + f * 16 + (lane & 15)][ks * 32 + (lane >> 4) * 8];
        bfv[f] = *(const short8*)&Bs[wn * 64 + f * 16 + (lane & 15)][ks * 32 + (lane >> 4) * 8];
      }
#pragma unroll
      for (int fm = 0; fm < 4; ++fm)
#pragma unroll
        for (int fn = 0; fn < 4; ++fn)
          acc[fm][fn] = __builtin_amdgcn_mfma_f32_16x16x32_bf16(af[fm], bfv[fn], acc[fm][fn], 0, 0, 0);
    }
  }

  // epilogue: D layout col=lane&15, row=(lane>>4)*4+reg
  const int lr = lane >> 4, lc = lane & 15;
#pragma unroll
  for (int fn = 0; fn < 4; ++fn) {
    const int col = n0 + wn * 64 + fn * 16 + lc;
    const float bv = bias[col];
#pragma unroll
    for (int fm = 0; fm < 4; ++fm) {
      const int rowb = m0 + wm * 64 + fm * 16 + lr * 4;
#pragma unroll
      for (int rg = 0; rg < 4; ++rg) {
        float vv = acc[fm][fn][rg] + bv;
        vv = fmaxf(vv, 0.0f);
        C[(size_t)(rowb + rg) * 512 + col] = f2bf(vv);
      }
    }
  }
}

// ---------------- final layer 512->3 + sigmoid, one wave per point ----------------
__global__ __launch_bounds__(256) void final_kernel(const u16* __restrict__ H,
                                                    const float* __restrict__ W4,
                                                    const float* __restrict__ b4,
                                                    float* __restrict__ out) {
  const int m = (int)((blockIdx.x * blockDim.x + threadIdx.x) >> 6);
  const int lane = (int)(threadIdx.x & 63);

  short8 hv = *(const short8*)(H + (size_t)m * 512 + lane * 8);
  float x[8];
#pragma unroll
  for (int e = 0; e < 8; ++e) x[e] = bf2f((u16)hv[e]);

  float s0 = 0, s1 = 0, s2 = 0;
  const float* w0 = W4 + 0 * 512 + lane * 8;
  const float* w1 = W4 + 1 * 512 + lane * 8;
  const float* w2 = W4 + 2 * 512 + lane * 8;
#pragma unroll
  for (int e = 0; e < 8; ++e) {
    s0 += x[e] * w0[e];
    s1 += x[e] * w1[e];
    s2 += x[e] * w2[e];
  }
#pragma unroll
  for (int off = 32; off; off >>= 1) {
    s0 += __shfl_xor(s0, off);
    s1 += __shfl_xor(s1, off);
    s2 += __shfl_xor(s2, off);
  }
  if (lane < 3) {
    float v = (lane == 0) ? s0 : (lane == 1 ? s1 : s2);
    v += b4[lane];
    out[(size_t)m * 3 + lane] = 1.0f / (1.0f + expf(-v));
  }
}

// ---------------- launch ----------------
extern "C" void kernel_launch(void* const* d_in, const int* in_sizes, int n_in,
                              void* d_out, int out_size, void* d_ws, size_t ws_size,
                              hipStream_t stream) {
  const float* pts  = (const float*)d_in[0];
  const float* nrm  = (const float*)d_in[1];
  const float* vdir = (const float*)d_in[2];
  const float* fv   = (const float*)d_in[3];
  const float* phys = (const float*)d_in[4];
  const float* rdir = (const float*)d_in[5];
  const float* cam  = (const float*)d_in[6];
  const float* v0 = (const float*)d_in[7];  const float* g0 = (const float*)d_in[8];  const float* b0 = (const float*)d_in[9];
  const float* v1 = (const float*)d_in[10]; const float* g1 = (const float*)d_in[11]; const float* b1 = (const float*)d_in[12];
  const float* v2 = (const float*)d_in[13]; const float* g2 = (const float*)d_in[14]; const float* b2 = (const float*)d_in[15];
  const float* v3 = (const float*)d_in[16]; const float* g3 = (const float*)d_in[17]; const float* b3 = (const float*)d_in[18];
  const float* v4 = (const float*)d_in[19]; const float* g4 = (const float*)d_in[20]; const float* b4 = (const float*)d_in[21];

  char* ws = (char*)d_ws;
  // layout (bytes): W0[512x576 bf16] W1..W3[512x512 bf16] W4[3x512 f32]
  //                 Pbuf[32768x12 f32] X[32768x576 bf16] H1[32768x512 bf16]
  u16*   W0 = (u16*)(ws + 0);
  u16*   W1 = (u16*)(ws + 589824);
  u16*   W2 = (u16*)(ws + 1114112);
  u16*   W3 = (u16*)(ws + 1638400);
  float* W4 = (float*)(ws + 2162688);
  float* Pb = (float*)(ws + 2168832);            // 32768*12*4 = 1572864 B
  u16*   X  = (u16*)(ws + 3741696);
  u16*   H1 = (u16*)(ws + 41490432);
  u16*   H2 = X;  // X not needed after layer 0; reuse as ping-pong buffer

  prep_w_bf16<<<512, 64, 0, stream>>>(v0, g0, W0, 517, 576);
  prep_w_bf16<<<512, 64, 0, stream>>>(v1, g1, W1, 512, 512);
  prep_w_bf16<<<512, 64, 0, stream>>>(v2, g2, W2, 512, 512);
  prep_w_bf16<<<512, 64, 0, stream>>>(v3, g3, W3, 512, 512);
  prep_w_f32<<<3, 64, 0, stream>>>(v4, g4, W4, 512);

  stats_kernel<<<128, 256, 0, stream>>>(pts, phys, cam, Pb);
  emb_kernel<<<8192, 256, 0, stream>>>(pts, nrm, vdir, fv, rdir, Pb, X);

  gemm_relu<9><<<dim3(4, 256), 256, 0, stream>>>(X,  W0, b0, H1);
  gemm_relu<8><<<dim3(4, 256), 256, 0, stream>>>(H1, W1, b1, H2);
  gemm_relu<8><<<dim3(4, 256), 256, 0, stream>>>(H2, W2, b2, H1);
  gemm_relu<8><<<dim3(4, 256), 256, 0, stream>>>(H1, W3, b3, H2);

  final_kernel<<<8192, 256, 0, stream>>>(H2, W4, b4, (float*)d_out);
}

// Round 4
// 212.104 us; speedup vs baseline: 1.6227x; 1.6227x over previous
//
#include <hip/hip_runtime.h>
#include <hip/hip_bf16.h>

typedef unsigned short u16;
typedef short short8 __attribute__((ext_vector_type(8)));
typedef float f32x4 __attribute__((ext_vector_type(4)));

// ---------------- helpers ----------------
static __device__ __forceinline__ u16 f2bf(float f) {
  unsigned u = __builtin_bit_cast(unsigned, f);
  unsigned r = (u + 0x7fffu + ((u >> 16) & 1u)) >> 16;  // RTNE
  return (u16)r;
}
static __device__ __forceinline__ float bf2f(u16 h) {
  unsigned u = ((unsigned)h) << 16;
  return __builtin_bit_cast(float, u);
}

// fast hw trig: v_sin_f32/v_cos_f32 take REVOLUTIONS, need explicit fract
static __device__ __forceinline__ float fsin(float x) {
  float r = x * 0.15915494309189535f;
  r = r - floorf(r);
  return __builtin_amdgcn_sinf(r);
}
static __device__ __forceinline__ float fcos(float x) {
  float r = x * 0.15915494309189535f;
  r = r - floorf(r);
  return __builtin_amdgcn_cosf(r);
}

// ---------------- weight prep: w = g * v / ||v_row||, store [N][Kpad] bf16 ----------------
__global__ void prep_w_bf16(const float* __restrict__ v, const float* __restrict__ g,
                            u16* __restrict__ out, int fan_in, int kpad) {
  const int row = blockIdx.x;
  const int lane = threadIdx.x;
  double s = 0.0;
  for (int k = lane; k < fan_in; k += 64) {
    double x = (double)v[(size_t)row * fan_in + k];
    s += x * x;
  }
#pragma unroll
  for (int off = 32; off; off >>= 1) s += __shfl_xor(s, off);
  double scale = (double)g[row] / sqrt(s);
  for (int k = lane; k < kpad; k += 64) {
    float wv = (k < fan_in) ? (float)((double)v[(size_t)row * fan_in + k] * scale) : 0.0f;
    out[(size_t)row * kpad + k] = f2bf(wv);
  }
}

__global__ void prep_w_f32(const float* __restrict__ v, const float* __restrict__ g,
                           float* __restrict__ out, int fan_in) {
  const int row = blockIdx.x;
  const int lane = threadIdx.x;
  double s = 0.0;
  for (int k = lane; k < fan_in; k += 64) {
    double x = (double)v[(size_t)row * fan_in + k];
    s += x * x;
  }
#pragma unroll
  for (int off = 32; off; off >>= 1) s += __shfl_xor(s, off);
  double scale = (double)g[row] / sqrt(s);
  for (int k = lane; k < fan_in; k += 64) {
    out[(size_t)row * fan_in + k] = (float)((double)v[(size_t)row * fan_in + k] * scale);
  }
}

// ---------------- phase A: ball-query scan, one WAVE per point ----------------
// idxbuf row (24 u16 per point): [0:20) neighbor indices (first-20 by index), [20] count
__global__ __launch_bounds__(256) void scan_kernel(
    const float* __restrict__ pts, const float* __restrict__ phys,
    u16* __restrict__ idxbuf) {
  const int m = (int)((blockIdx.x * blockDim.x + threadIdx.x) >> 6);
  const int lane = (int)(threadIdx.x & 63);

  const double qx = (double)pts[m * 3 + 0];
  const double qy = (double)pts[m * 3 + 1];
  const double qz = (double)pts[m * 3 + 2];

  u16* __restrict__ row = idxbuf + (size_t)m * 24;

  int found = 0;
  for (int base = 0; base < 4096 && found < 20; base += 64) {
    const int j = base + lane;
    const double px = (double)phys[j * 3 + 0];
    const double py = (double)phys[j * 3 + 1];
    const double pz = (double)phys[j * 3 + 2];
    const double dx = px - qx, dy = py - qy, dz = pz - qz;
    const double d2 = dx * dx + dy * dy + dz * dz;   // fp64: selection must match np ref
    const bool valid = d2 < 81.0;
    const unsigned long long mb = __ballot(valid);
    const int rank = found + __popcll(mb & ((1ull << lane) - 1ull));
    if (valid && rank < 20) row[rank] = (u16)j;
    found += __popcll(mb);
    if (found > 20) found = 20;
  }
  if (lane == 0) row[20] = (u16)found;
}

// ---------------- phase B: gather + stats, one LANE per point, fixed 20 slots ----------------
// Pbuf layout per point (12 f32): density, spx,spy,spz, vax,vay,vaz, sdx,sdy,sdz, 0,0
__global__ __launch_bounds__(256) void gstats_kernel(
    const float* __restrict__ pts, const float* __restrict__ phys,
    const float* __restrict__ cam, const u16* __restrict__ idxbuf,
    float* __restrict__ Pbuf) {
  const int i = blockIdx.x * 256 + threadIdx.x;

  const double qx = (double)pts[i * 3 + 0];
  const double qy = (double)pts[i * 3 + 1];
  const double qz = (double)pts[i * 3 + 2];

  const u16* __restrict__ row = idxbuf + (size_t)i * 24;
  const int cnt = (int)row[20];

  int nnn = 0;
  double w_sum = 0, wpx = 0, wpy = 0, wpz = 0;
  double Sx = 0, Sy = 0, Sz = 0, Qx = 0, Qy = 0, Qz = 0;

#pragma unroll
  for (int s = 0; s < 20; ++s) {
    if (s < cnt) {
      const int j = (int)row[s];
      const double px = (double)phys[j * 3 + 0];
      const double py = (double)phys[j * 3 + 1];
      const double pz = (double)phys[j * 3 + 2];
      const double dx = px - qx, dy = py - qy, dz = pz - qz;
      const double d2 = dx * dx + dy * dy + dz * dz;
      const float d2f = (float)d2;
      float wf = 1.0f - d2f * sqrtf(d2f) * (1.0f / 729.0f);
      if (wf < 0.0f) wf = 0.0f;
      const double w = (double)wf;
      w_sum += w; wpx += w * px; wpy += w * py; wpz += w * pz;
      if (d2 != 0.0) {
        nnn += 1;
        Sx += dx; Sy += dy; Sz += dz;
        Qx += dx * dx; Qy += dy * dy; Qz += dz * dz;
      }
    }
  }

  // padding slots: neighbors = 0 -> dd = ||q||
  {
    const float q2f = (float)(qx * qx + qy * qy + qz * qz);
    float wpad = 1.0f - q2f * sqrtf(q2f) * (1.0f / 729.0f);
    if (wpad < 0.0f) wpad = 0.0f;
    w_sum += (double)(20 - cnt) * (double)wpad;
  }

  const double inv_denom = 1.0 / (w_sum + 1e-12);
  const double sposx = wpx * inv_denom, sposy = wpy * inv_denom, sposz = wpz * inv_denom;

  const double inv_nd = 1.0 / ((double)nnn + 1e-12);
  const double vmx = Sx * inv_nd, vmy = Sy * inv_nd, vmz = Sz * inv_nd;
  const float vax = (float)((Qx - 2.0 * vmx * Sx + (double)nnn * vmx * vmx) * inv_nd);
  const float vay = (float)((Qy - 2.0 * vmy * Sy + (double)nnn * vmy * vmy) * inv_nd);
  const float vaz = (float)((Qz - 2.0 * vmz * Sz + (double)nnn * vmz * vmz) * inv_nd);

  const double ddx = sposx - (double)cam[0];
  const double ddy = sposy - (double)cam[1];
  const double ddz = sposz - (double)cam[2];
  const double inv_dnm = 1.0 / sqrt(ddx * ddx + ddy * ddy + ddz * ddz);

  f32x4* out = (f32x4*)(Pbuf + (size_t)i * 12);
  f32x4 o0, o1, o2;
  o0[0] = (float)w_sum; o0[1] = (float)sposx; o0[2] = (float)sposy; o0[3] = (float)sposz;
  o1[0] = vax; o1[1] = vay; o1[2] = vaz; o1[3] = (float)(ddx * inv_dnm);
  o2[0] = (float)(ddy * inv_dnm); o2[1] = (float)(ddz * inv_dnm); o2[2] = 0.0f; o2[3] = 0.0f;
  out[0] = o0; out[1] = o1; out[2] = o2;
}

// ---------------- embeddings ----------------
static __device__ __forceinline__ float embed3(float a, float b, float c, int e) {
  // layout: [a,b,c, sin(2^0 a),sin(2^0 b),sin(2^0 c),cos(2^0 a),..., f=0..F-1]
  if (e < 3) return e == 0 ? a : (e == 1 ? b : c);
  int u = e - 3;
  int f = u / 6;
  int r = u - f * 6;
  int ci = r % 3;
  float x = ci == 0 ? a : (ci == 1 ? b : c);
  float xf = x * (float)(1 << f);   // exact (power of 2)
  return (r < 3) ? fsin(xf) : fcos(xf);
}
static __device__ __forceinline__ float embed1(float a, int e) {
  if (e == 0) return a;
  int u = e - 1;
  int f = u >> 1;
  float xf = a * (float)(1 << f);
  return (u & 1) ? fcos(xf) : fsin(xf);
}

// ---------------- embed + write X: one wave per point ----------------
// X row layout (576 cols, zero pad beyond 517):
// [0:3) points  [3:6) view_dirs  [6:9) normals  [9:265) feature_vectors
// [265:328) emb(points,10) [328:337) emb(density,4) [337:400) emb(spos,10)
// [400:463) emb(var,10) [463:490) emb(ray_dir,4) [490:517) emb(sdir,4)
__global__ __launch_bounds__(256) void emb_kernel(
    const float* __restrict__ pts, const float* __restrict__ nrm,
    const float* __restrict__ vdir, const float* __restrict__ fv,
    const float* __restrict__ rdir, const float* __restrict__ Pbuf,
    u16* __restrict__ X) {
  const int m = (int)((blockIdx.x * blockDim.x + threadIdx.x) >> 6);
  const int lane = (int)(threadIdx.x & 63);

  const f32x4* pb = (const f32x4*)(Pbuf + (size_t)m * 12);
  const f32x4 s0 = pb[0];
  const f32x4 s1 = pb[1];
  const f32x4 s2 = pb[2];
  const float density = s0[0];
  const float spx = s0[1], spy = s0[2], spz = s0[3];
  const float vax = s1[0], vay = s1[1], vaz = s1[2];
  const float sdx = s1[3], sdy = s2[0], sdz = s2[1];

  const float fqx = pts[m * 3 + 0], fqy = pts[m * 3 + 1], fqz = pts[m * 3 + 2];
  const int ray = m >> 7;  // reps = 32768/256 = 128
  const float rdx = rdir[ray * 3 + 0], rdy = rdir[ray * 3 + 1], rdz = rdir[ray * 3 + 2];

  u16* __restrict__ xrow = X + (size_t)m * 576;
  for (int k = lane; k < 576; k += 64) {
    float val;
    if (k < 9) {
      if (k < 3) val = (k == 0) ? fqx : (k == 1 ? fqy : fqz);
      else if (k < 6) val = vdir[m * 3 + (k - 3)];
      else val = nrm[m * 3 + (k - 6)];
    } else if (k < 265) {
      val = fv[(size_t)m * 256 + (k - 9)];
    } else if (k < 328) {
      val = embed3(fqx, fqy, fqz, k - 265);
    } else if (k < 337) {
      val = embed1(density, k - 328);
    } else if (k < 400) {
      val = embed3(spx, spy, spz, k - 337);
    } else if (k < 463) {
      val = embed3(vax, vay, vaz, k - 400);
    } else if (k < 490) {
      val = embed3(rdx, rdy, rdz, k - 463);
    } else if (k < 517) {
      val = embed3(sdx, sdy, sdz, k - 490);
    } else {
      val = 0.0f;
    }
    xrow[k] = f2bf(val);
  }
}

// ---------------- bf16 MFMA GEMM: C[M,512] = relu(A[M,K] * B[N,K]^T + bias) ----------------
// A row-major stride K; B (weights) row-major [N][K]; C bf16 [M][512].
// Block: 256 threads = 4 waves (2x2), tile 128x128, BK=64.
template <int KTILES>
__global__ __launch_bounds__(256) void gemm_relu(const u16* __restrict__ A,
                                                 const u16* __restrict__ B,
                                                 const float* __restrict__ bias,
                                                 u16* __restrict__ C) {
  constexpr int K = KTILES * 64;
  __shared__ __align__(16) u16 As[128][72];  // +8 pad: 2-way (free) bank pattern
  __shared__ __align__(16) u16 Bs[128][72];

  const int t = threadIdx.x;
  const int lane = t & 63;
  const int wid = t >> 6;
  const int wm = wid >> 1, wn = wid & 1;
  const int n0 = blockIdx.x * 128;
  const int m0 = blockIdx.y * 128;

  f32x4 acc[4][4] = {};

  for (int kt = 0; kt < KTILES; ++kt) {
    const int k0 = kt * 64;
    __syncthreads();
#pragma unroll
    for (int i = 0; i < 4; ++i) {
      int slot = i * 256 + t;       // 0..1023
      int rr = slot >> 3;           // 0..127
      int cc = slot & 7;            // 0..7 (16B chunks)
      short8 av = *(const short8*)(A + (size_t)(m0 + rr) * K + k0 + cc * 8);
      short8 bv = *(const short8*)(B + (size_t)(n0 + rr) * K + k0 + cc * 8);
      *(short8*)&As[rr][cc * 8] = av;
      *(short8*)&Bs[rr][cc * 8] = bv;
    }
    __syncthreads();
#pragma unroll
    for (int ks = 0; ks < 2; ++ks) {
      short8 af[4], bfv[4];
#pragma unroll
      for (int f = 0; f < 4; ++f) {
        af[f] = *(const short8*)&As[wm * 64 + f * 16 + (lane & 15)][ks * 32 + (lane >> 4) * 8];
        bfv[f] = *(const short8*)&Bs[wn * 64 + f * 16 + (lane & 15)][ks * 32 + (lane >> 4) * 8];
      }
#pragma unroll
      for (int fm = 0; fm < 4; ++fm)
#pragma unroll
        for (int fn = 0; fn < 4; ++fn)
          acc[fm][fn] = __builtin_amdgcn_mfma_f32_16x16x32_bf16(af[fm], bfv[fn], acc[fm][fn], 0, 0, 0);
    }
  }

  // epilogue: D layout col=lane&15, row=(lane>>4)*4+reg
  const int lr = lane >> 4, lc = lane & 15;
#pragma unroll
  for (int fn = 0; fn < 4; ++fn) {
    const int col = n0 + wn * 64 + fn * 16 + lc;
    const float bv = bias[col];
#pragma unroll
    for (int fm = 0; fm < 4; ++fm) {
      const int rowb = m0 + wm * 64 + fm * 16 + lr * 4;
#pragma unroll
      for (int rg = 0; rg < 4; ++rg) {
        float vv = acc[fm][fn][rg] + bv;
        vv = fmaxf(vv, 0.0f);
        C[(size_t)(rowb + rg) * 512 + col] = f2bf(vv);
      }
    }
  }
}

// ---------------- final layer 512->3 + sigmoid, one wave per point ----------------
__global__ __launch_bounds__(256) void final_kernel(const u16* __restrict__ H,
                                                    const float* __restrict__ W4,
                                                    const float* __restrict__ b4,
                                                    float* __restrict__ out) {
  const int m = (int)((blockIdx.x * blockDim.x + threadIdx.x) >> 6);
  const int lane = (int)(threadIdx.x & 63);

  short8 hv = *(const short8*)(H + (size_t)m * 512 + lane * 8);
  float x[8];
#pragma unroll
  for (int e = 0; e < 8; ++e) x[e] = bf2f((u16)hv[e]);

  float s0 = 0, s1 = 0, s2 = 0;
  const float* w0 = W4 + 0 * 512 + lane * 8;
  const float* w1 = W4 + 1 * 512 + lane * 8;
  const float* w2 = W4 + 2 * 512 + lane * 8;
#pragma unroll
  for (int e = 0; e < 8; ++e) {
    s0 += x[e] * w0[e];
    s1 += x[e] * w1[e];
    s2 += x[e] * w2[e];
  }
#pragma unroll
  for (int off = 32; off; off >>= 1) {
    s0 += __shfl_xor(s0, off);
    s1 += __shfl_xor(s1, off);
    s2 += __shfl_xor(s2, off);
  }
  if (lane < 3) {
    float v = (lane == 0) ? s0 : (lane == 1 ? s1 : s2);
    v += b4[lane];
    out[(size_t)m * 3 + lane] = 1.0f / (1.0f + expf(-v));
  }
}

// ---------------- launch ----------------
extern "C" void kernel_launch(void* const* d_in, const int* in_sizes, int n_in,
                              void* d_out, int out_size, void* d_ws, size_t ws_size,
                              hipStream_t stream) {
  const float* pts  = (const float*)d_in[0];
  const float* nrm  = (const float*)d_in[1];
  const float* vdir = (const float*)d_in[2];
  const float* fv   = (const float*)d_in[3];
  const float* phys = (const float*)d_in[4];
  const float* rdir = (const float*)d_in[5];
  const float* cam  = (const float*)d_in[6];
  const float* v0 = (const float*)d_in[7];  const float* g0 = (const float*)d_in[8];  const float* b0 = (const float*)d_in[9];
  const float* v1 = (const float*)d_in[10]; const float* g1 = (const float*)d_in[11]; const float* b1 = (const float*)d_in[12];
  const float* v2 = (const float*)d_in[13]; const float* g2 = (const float*)d_in[14]; const float* b2 = (const float*)d_in[15];
  const float* v3 = (const float*)d_in[16]; const float* g3 = (const float*)d_in[17]; const float* b3 = (const float*)d_in[18];
  const float* v4 = (const float*)d_in[19]; const float* g4 = (const float*)d_in[20]; const float* b4 = (const float*)d_in[21];

  char* ws = (char*)d_ws;
  // layout (bytes): W0[512x576 bf16] W1..W3[512x512 bf16] W4[3x512 f32]
  //                 Idx[32768x24 u16] Pbuf[32768x12 f32] X[32768x576 bf16] H1[32768x512 bf16]
  u16*   W0 = (u16*)(ws + 0);
  u16*   W1 = (u16*)(ws + 589824);
  u16*   W2 = (u16*)(ws + 1114112);
  u16*   W3 = (u16*)(ws + 1638400);
  float* W4 = (float*)(ws + 2162688);
  u16*   Ix = (u16*)(ws + 2168832);              // 32768*24*2 = 1572864 B
  float* Pb = (float*)(ws + 3741696);            // 32768*12*4 = 1572864 B
  u16*   X  = (u16*)(ws + 5314560);
  u16*   H1 = (u16*)(ws + 43063296);
  u16*   H2 = X;  // X not needed after layer 0; reuse as ping-pong buffer

  prep_w_bf16<<<512, 64, 0, stream>>>(v0, g0, W0, 517, 576);
  prep_w_bf16<<<512, 64, 0, stream>>>(v1, g1, W1, 512, 512);
  prep_w_bf16<<<512, 64, 0, stream>>>(v2, g2, W2, 512, 512);
  prep_w_bf16<<<512, 64, 0, stream>>>(v3, g3, W3, 512, 512);
  prep_w_f32<<<3, 64, 0, stream>>>(v4, g4, W4, 512);

  scan_kernel<<<8192, 256, 0, stream>>>(pts, phys, Ix);
  gstats_kernel<<<128, 256, 0, stream>>>(pts, phys, cam, Ix, Pb);
  emb_kernel<<<8192, 256, 0, stream>>>(pts, nrm, vdir, fv, rdir, Pb, X);

  gemm_relu<9><<<dim3(4, 256), 256, 0, stream>>>(X,  W0, b0, H1);
  gemm_relu<8><<<dim3(4, 256), 256, 0, stream>>>(H1, W1, b1, H2);
  gemm_relu<8><<<dim3(4, 256), 256, 0, stream>>>(H2, W2, b2, H1);
  gemm_relu<8><<<dim3(4, 256), 256, 0, stream>>>(H1, W3, b3, H2);

  final_kernel<<<8192, 256, 0, stream>>>(H2, W4, b4, (float*)d_out);
}